// Round 1
// baseline (2048.834 us; speedup 1.0000x reference)
//
#include <hip/hip_runtime.h>
#include <hip/hip_bf16.h>
#include <cstdint>
#include <cstddef>

typedef unsigned short u16;
typedef __attribute__((ext_vector_type(8))) short bf16x8;   // MFMA A/B operand (8 bf16 in 4 VGPRs)
typedef __attribute__((ext_vector_type(4))) float f32x4;    // MFMA C/D operand
typedef __attribute__((ext_vector_type(8))) unsigned short u16x8;
typedef __attribute__((ext_vector_type(4))) unsigned short u16x4;

__device__ inline u16 f2bf(float f) {
  union { float f; uint32_t u; } v; v.f = f;
  uint32_t r = v.u + 0x7fffu + ((v.u >> 16) & 1u);   // RNE
  return (u16)(r >> 16);
}

// ---------------------------------------------------------------------------
// C[m,n] = sum_k A[m,k] * W[n,k] + bias[n]     (torch Linear: x @ W.T + b)
// A: [8192 x 1024] (fp32 or bf16 per A_BF16), W: [1024 x 1024] fp32 row-major
// Tile 128x128, BK=64, 256 threads (4 waves, each wave a 64x64 quadrant).
// ---------------------------------------------------------------------------
template<bool OUT_F32, bool A_BF16>
__global__ __launch_bounds__(256)
void gemm_bt(const void* __restrict__ Ap, const float* __restrict__ W,
             const float* __restrict__ bias, void* __restrict__ Cout) {
  const int K = 1024, N = 1024;
  const int m0 = blockIdx.y * 128, n0 = blockIdx.x * 128;
  __shared__ u16 As[128][72];   // +8 pad: row stride 144B breaks bank aliasing, keeps 16B align
  __shared__ u16 Bs[128][72];
  const int tid  = threadIdx.x;
  const int wave = tid >> 6, lane = tid & 63;
  const int quad = lane >> 4, l16 = lane & 15;
  const int wr = (wave >> 1) * 64, wc = (wave & 1) * 64;

  f32x4 acc[4][4] = {};

  for (int k0 = 0; k0 < K; k0 += 64) {
    __syncthreads();
    if constexpr (A_BF16) {
      const u16* Ab = (const u16*)Ap;
      for (int c = tid; c < 1024; c += 256) {          // 128 rows x 8 chunks(8 bf16)
        int row = c >> 3, c8 = c & 7;
        *(u16x8*)&As[row][c8 * 8] =
            *(const u16x8*)(Ab + (size_t)(m0 + row) * K + k0 + c8 * 8);
      }
    } else {
      const float* Af = (const float*)Ap;
      for (int c = tid; c < 2048; c += 256) {          // 128 rows x 16 chunks(4 f32)
        int row = c >> 4, c4 = c & 15;
        float4 a = *(const float4*)(Af + (size_t)(m0 + row) * K + k0 + c4 * 4);
        u16x4 ua = { f2bf(a.x), f2bf(a.y), f2bf(a.z), f2bf(a.w) };
        *(u16x4*)&As[row][c4 * 4] = ua;
      }
    }
    for (int c = tid; c < 2048; c += 256) {
      int row = c >> 4, c4 = c & 15;
      float4 b = *(const float4*)(W + (size_t)(n0 + row) * K + k0 + c4 * 4);
      u16x4 ub = { f2bf(b.x), f2bf(b.y), f2bf(b.z), f2bf(b.w) };
      *(u16x4*)&Bs[row][c4 * 4] = ub;
    }
    __syncthreads();

#pragma unroll
    for (int ks = 0; ks < 2; ks++) {
      bf16x8 af[4], bg[4];
#pragma unroll
      for (int i = 0; i < 4; i++)
        af[i] = *(const bf16x8*)&As[wr + i * 16 + l16][ks * 32 + quad * 8];
#pragma unroll
      for (int j = 0; j < 4; j++)
        bg[j] = *(const bf16x8*)&Bs[wc + j * 16 + l16][ks * 32 + quad * 8];
#pragma unroll
      for (int i = 0; i < 4; i++)
#pragma unroll
        for (int j = 0; j < 4; j++)
          acc[i][j] = __builtin_amdgcn_mfma_f32_16x16x32_bf16(af[i], bg[j], acc[i][j], 0, 0, 0);
    }
  }

  // epilogue: C/D layout row = quad*4 + r, col = l16
#pragma unroll
  for (int i = 0; i < 4; i++)
#pragma unroll
    for (int j = 0; j < 4; j++) {
      int col = n0 + wc + j * 16 + l16;
      float bv = bias[col];
#pragma unroll
      for (int r = 0; r < 4; r++) {
        int row = m0 + wr + i * 16 + quad * 4 + r;
        float v = acc[i][j][r] + bv;
        if constexpr (OUT_F32) ((float*)Cout)[(size_t)row * N + col] = v;
        else                   ((u16*)Cout)[(size_t)row * N + col]   = f2bf(v);
      }
    }
}

// ---------------------------------------------------------------------------
// Vp [b*2048+kk][h*64+d] bf16  ->  Vt [bh][d][kk=2048] bf16  (per-head transpose)
// ---------------------------------------------------------------------------
__global__ __launch_bounds__(256)
void transpose_v(const u16* __restrict__ Vp, u16* __restrict__ Vt) {
  const int bh = blockIdx.y, b = bh >> 4, h = bh & 15;
  const int kk0 = blockIdx.x * 64;
  __shared__ u16 t[64][72];
  const int tid = threadIdx.x;
  for (int c = tid; c < 512; c += 256) {       // 64 kk rows x 8 chunks(8 d)
    int kk = c >> 3, d8 = c & 7;
    *(u16x8*)&t[kk][d8 * 8] =
        *(const u16x8*)(Vp + (size_t)(b * 2048 + kk0 + kk) * 1024 + h * 64 + d8 * 8);
  }
  __syncthreads();
  for (int c = tid; c < 512; c += 256) {       // 64 d rows x 8 chunks(8 kk)
    int d = c >> 3, k8 = c & 7;
    u16x8 v;
#pragma unroll
    for (int j = 0; j < 8; j++) v[j] = t[k8 * 8 + j][d];
    *(u16x8*)(Vt + ((size_t)bh * 64 + d) * 2048 + kk0 + k8 * 8) = v;
  }
}

// ---------------------------------------------------------------------------
// Fused attention per (bh, q-tile of 128): two passes over K-tiles of 64.
// Pass 1: l[q] = sum_kk exp(s)   (no max-subtraction: |s|<~6.5, fp32-safe)
// Pass 2: recompute s, w = exp(s)/l -> write attw (fp32, HBM, once) and Ws
//         (bf16, LDS) -> PV MFMA accumulates O.  O -> AO bf16 [8192][1024].
// ---------------------------------------------------------------------------
__global__ __launch_bounds__(256)
void attn(const u16* __restrict__ Qp, const u16* __restrict__ Kp,
          const u16* __restrict__ Vt, float* __restrict__ attw,
          u16* __restrict__ AO) {
  const int bh = blockIdx.y, b = bh >> 4, h = bh & 15;
  const int q0 = blockIdx.x * 128;
  const float scale = 0.125f;     // 1/sqrt(64)

  __shared__ u16 Qs[128][72];     // q x d
  __shared__ u16 Ks[64][72];      // kk x d
  __shared__ u16 Vs[64][72];      // d x kk   (from pre-transposed Vt)
  __shared__ u16 Ws[128][72];     // q x kk   (weights, C-layout -> A-layout via LDS)
  __shared__ float lsum[128];

  const int tid  = threadIdx.x;
  const int wave = tid >> 6, lane = tid & 63;
  const int quad = lane >> 4, l16 = lane & 15;

  // stage Q tile once (consumed after the barriers in the first pass-1 iter)
  for (int c = tid; c < 1024; c += 256) {
    int row = c >> 3, c8 = c & 7;
    *(u16x8*)&Qs[row][c8 * 8] =
        *(const u16x8*)(Qp + (size_t)(b * 2048 + q0 + row) * 1024 + h * 64 + c8 * 8);
  }

  float es[2][4] = {};            // per-lane exp-sum partials [row-tile][r]

  // ---------------- pass 1: row sums ----------------
  for (int kt = 0; kt < 2048; kt += 64) {
    __syncthreads();
    for (int c = tid; c < 512; c += 256) {
      int row = c >> 3, c8 = c & 7;
      *(u16x8*)&Ks[row][c8 * 8] =
          *(const u16x8*)(Kp + (size_t)(b * 2048 + kt + row) * 1024 + h * 64 + c8 * 8);
    }
    __syncthreads();
    f32x4 acc[2][4] = {};
#pragma unroll
    for (int ks = 0; ks < 2; ks++) {
      bf16x8 af[2], bg[4];
#pragma unroll
      for (int i = 0; i < 2; i++)
        af[i] = *(const bf16x8*)&Qs[wave * 32 + i * 16 + l16][ks * 32 + quad * 8];
#pragma unroll
      for (int j = 0; j < 4; j++)
        bg[j] = *(const bf16x8*)&Ks[j * 16 + l16][ks * 32 + quad * 8];
#pragma unroll
      for (int i = 0; i < 2; i++)
#pragma unroll
        for (int j = 0; j < 4; j++)
          acc[i][j] = __builtin_amdgcn_mfma_f32_16x16x32_bf16(af[i], bg[j], acc[i][j], 0, 0, 0);
    }
#pragma unroll
    for (int i = 0; i < 2; i++)
#pragma unroll
      for (int j = 0; j < 4; j++)
#pragma unroll
        for (int r = 0; r < 4; r++)
          es[i][r] += __expf(acc[i][j][r] * scale);
  }
  // reduce across the 16 lanes of each quad (each quad owns rows quad*4+r)
#pragma unroll
  for (int off = 1; off < 16; off <<= 1)
#pragma unroll
    for (int i = 0; i < 2; i++)
#pragma unroll
      for (int r = 0; r < 4; r++)
        es[i][r] += __shfl_xor(es[i][r], off, 64);
  if (l16 == 0)
#pragma unroll
    for (int i = 0; i < 2; i++)
#pragma unroll
      for (int r = 0; r < 4; r++)
        lsum[wave * 32 + i * 16 + quad * 4 + r] = es[i][r];
  __syncthreads();
  float linv[2][4];
#pragma unroll
  for (int i = 0; i < 2; i++)
#pragma unroll
    for (int r = 0; r < 4; r++)
      linv[i][r] = 1.0f / lsum[wave * 32 + i * 16 + quad * 4 + r];

  // ---------------- pass 2: weights out + PV ----------------
  f32x4 oacc[2][4] = {};
  for (int kt = 0; kt < 2048; kt += 64) {
    __syncthreads();   // protects Ks/Vs/Ws from prev iteration's readers
    for (int c = tid; c < 512; c += 256) {
      int row = c >> 3, c8 = c & 7;
      *(u16x8*)&Ks[row][c8 * 8] =
          *(const u16x8*)(Kp + (size_t)(b * 2048 + kt + row) * 1024 + h * 64 + c8 * 8);
    }
    for (int c = tid; c < 512; c += 256) {
      int d = c >> 3, k8 = c & 7;
      *(u16x8*)&Vs[d][k8 * 8] =
          *(const u16x8*)(Vt + ((size_t)bh * 64 + d) * 2048 + kt + k8 * 8);
    }
    __syncthreads();
    f32x4 acc[2][4] = {};
#pragma unroll
    for (int ks = 0; ks < 2; ks++) {
      bf16x8 af[2], bg[4];
#pragma unroll
      for (int i = 0; i < 2; i++)
        af[i] = *(const bf16x8*)&Qs[wave * 32 + i * 16 + l16][ks * 32 + quad * 8];
#pragma unroll
      for (int j = 0; j < 4; j++)
        bg[j] = *(const bf16x8*)&Ks[j * 16 + l16][ks * 32 + quad * 8];
#pragma unroll
      for (int i = 0; i < 2; i++)
#pragma unroll
        for (int j = 0; j < 4; j++)
          acc[i][j] = __builtin_amdgcn_mfma_f32_16x16x32_bf16(af[i], bg[j], acc[i][j], 0, 0, 0);
    }
    // w = exp(s)/l : write fp32 to HBM (the mandatory 1.07GB), bf16 to Ws
#pragma unroll
    for (int i = 0; i < 2; i++)
#pragma unroll
      for (int j = 0; j < 4; j++) {
        int colg = kt + j * 16 + l16;
#pragma unroll
        for (int r = 0; r < 4; r++) {
          int rowl = wave * 32 + i * 16 + quad * 4 + r;
          float w = __expf(acc[i][j][r] * scale) * linv[i][r];
          attw[((size_t)bh * 2048 + q0 + rowl) * 2048 + colg] = w;
          Ws[rowl][j * 16 + l16] = f2bf(w);
        }
      }
    __syncthreads();
    // PV: O[q][d] += Ws[q][kk] * Vs[d][kk]^T
#pragma unroll
    for (int ks = 0; ks < 2; ks++) {
      bf16x8 af[2], bg[4];
#pragma unroll
      for (int i = 0; i < 2; i++)
        af[i] = *(const bf16x8*)&Ws[wave * 32 + i * 16 + l16][ks * 32 + quad * 8];
#pragma unroll
      for (int j = 0; j < 4; j++)
        bg[j] = *(const bf16x8*)&Vs[j * 16 + l16][ks * 32 + quad * 8];
#pragma unroll
      for (int i = 0; i < 2; i++)
#pragma unroll
        for (int j = 0; j < 4; j++)
          oacc[i][j] = __builtin_amdgcn_mfma_f32_16x16x32_bf16(af[i], bg[j], oacc[i][j], 0, 0, 0);
    }
  }

  // epilogue: AO[b*2048+q][h*64+d] bf16  (heads re-interleaved for final GEMM)
#pragma unroll
  for (int i = 0; i < 2; i++)
#pragma unroll
    for (int j = 0; j < 4; j++) {
      int d = j * 16 + l16;
#pragma unroll
      for (int r = 0; r < 4; r++) {
        int rowl = wave * 32 + i * 16 + quad * 4 + r;
        AO[(size_t)(b * 2048 + q0 + rowl) * 1024 + h * 64 + d] = f2bf(oacc[i][j][r]);
      }
    }
}

// ---------------------------------------------------------------------------
extern "C" void kernel_launch(void* const* d_in, const int* in_sizes, int n_in,
                              void* d_out, int out_size, void* d_ws, size_t ws_size,
                              hipStream_t stream) {
  const float* query = (const float*)d_in[0];
  const float* key   = (const float*)d_in[1];
  const float* value = (const float*)d_in[2];
  const float* Wq = (const float*)d_in[3];
  const float* bq = (const float*)d_in[4];
  const float* Wk = (const float*)d_in[5];
  const float* bk = (const float*)d_in[6];
  const float* Wv = (const float*)d_in[7];
  const float* bv = (const float*)d_in[8];
  const float* Wo = (const float*)d_in[9];
  const float* bo = (const float*)d_in[10];

  float* out  = (float*)d_out;                       // [4,2048,1024]
  float* attw = out + (size_t)8192 * 1024;           // [4,16,2048,2048]

  // workspace layout (80 MiB total)
  u16* Qp = (u16*)d_ws;                              // [8192][1024] bf16
  u16* Kp = Qp + (size_t)8192 * 1024;
  u16* Vp = Kp + (size_t)8192 * 1024;
  u16* Vt = Vp + (size_t)8192 * 1024;                // [64][64][2048] bf16
  u16* AO = Vt + (size_t)64 * 64 * 2048;             // [8192][1024] bf16

  dim3 blk(256);
  dim3 gg(8, 64);     // N/128, M/128
  gemm_bt<false, false><<<gg, blk, 0, stream>>>(query, Wq, bq, Qp);
  gemm_bt<false, false><<<gg, blk, 0, stream>>>(key,   Wk, bk, Kp);
  gemm_bt<false, false><<<gg, blk, 0, stream>>>(value, Wv, bv, Vp);
  transpose_v<<<dim3(32, 64), blk, 0, stream>>>(Vp, Vt);
  attn<<<dim3(16, 64), blk, 0, stream>>>(Qp, Kp, Vt, attw, AO);
  gemm_bt<true, true><<<gg, blk, 0, stream>>>(AO, Wo, bo, (void*)out);
}